// Round 26
// baseline (1180.934 us; speedup 1.0000x reference)
//
#include <hip/hip_runtime.h>
#include <hip/hip_bf16.h>

// Round 26: 64-row tiles (2x blocks, lower VGPR -> latency hiding) + fused
// dual-gate GRU kernel (R,Z in one pass over q,hp -> halves gate traffic).
// Semantics locked (r23/r24/r25 PASS): f32 out, pairing A, listed GCN,
// torch r,z,n GRU. CSR gather unchanged.

__device__ __forceinline__ float sigf(float x) { return 1.0f / (1.0f + __expf(-x)); }

__global__ __launch_bounds__(256) void k_fill(float* o, long long n, float v) {
  long long i = (long long)blockIdx.x * 256 + threadIdx.x;
  if (i < n) o[i] = v;
}

// ---------------- CSR build (pairing A: src=ei[e], dst=ei[E+e]) ----------------

__global__ __launch_bounds__(256) void k_hist(const int* __restrict__ dstp, int* __restrict__ hist, int E) {
  int e = blockIdx.x * 256 + threadIdx.x;
  if (e < E) atomicAdd(&hist[dstp[e]], 1);
}

__global__ __launch_bounds__(256) void k_scan1(const int* __restrict__ hist, int* __restrict__ part,
                                               int* __restrict__ bsum, int n) {
  __shared__ int sh[256];
  int tid = threadIdx.x;
  int i = blockIdx.x * 256 + tid;
  int v = (i < n) ? hist[i] : 0;
  sh[tid] = v; __syncthreads();
  for (int off = 1; off < 256; off <<= 1) {
    int t = (tid >= off) ? sh[tid - off] : 0;
    __syncthreads();
    sh[tid] += t;
    __syncthreads();
  }
  if (i < n) part[i] = sh[tid] - v;
  if (tid == 255) bsum[blockIdx.x] = sh[255];
}

__global__ __launch_bounds__(512) void k_scan2(int* bs, int nb) {
  __shared__ int sh[512];
  int tid = threadIdx.x;
  int v = (tid < nb) ? bs[tid] : 0;
  sh[tid] = v; __syncthreads();
  for (int off = 1; off < 512; off <<= 1) {
    int t = (tid >= off) ? sh[tid - off] : 0;
    __syncthreads();
    sh[tid] += t;
    __syncthreads();
  }
  if (tid < nb) bs[tid] = sh[tid] - v;
}

__global__ __launch_bounds__(256) void k_scan3(const int* __restrict__ part, const int* __restrict__ bs,
                                               const int* __restrict__ hist, int* __restrict__ offs,
                                               int* __restrict__ cursor, float* __restrict__ dinv,
                                               int n, int E) {
  int i = blockIdx.x * 256 + threadIdx.x;
  if (i < n) {
    int o = part[i] + bs[i >> 8];
    offs[i] = o;
    cursor[i] = o;
    dinv[i] = rsqrtf((float)hist[i] + 1.0f);   // +1 self-loop
  } else if (i == n) {
    offs[n] = E;
  }
}

__global__ __launch_bounds__(256) void k_sort(const int* __restrict__ srcp, const int* __restrict__ dstp,
                                              int* cursor, int* __restrict__ ssrc, int E) {
  int e = blockIdx.x * 256 + threadIdx.x;
  if (e < E) {
    int d = dstp[e];
    int pos = atomicAdd(&cursor[d], 1);
    ssrc[pos] = srcp[e];
  }
}

// ---------------- 64x128 tiled GEMM pieces (KC=32, 256 thr, micro 4x8) ----------------
// tr=tid>>4 -> rows rr=tr*4..+3 ; tc=tid&15 -> cols cl=tc*4, ch=64+tc*4

#define KC 32

__device__ __forceinline__ void stage_A64(const float* __restrict__ A, float (&At)[KC][68],
                                          int r0, int kk, int nrows, int tid) {
  #pragma unroll
  for (int it = 0; it < 8; ++it) {
    int idx = tid + it * 256;          // 2048 = 64 rows x 32 k
    int r = idx >> 5, kl = idx & 31;
    int gr = r0 + r;
    At[kl][r] = (gr < nrows) ? A[(long long)gr * 128 + kk + kl] : 0.f;
  }
}

__device__ __forceinline__ void stage_W_nn(const float* __restrict__ W, float (&Ws)[KC][132],
                                           int kk, int tid) {
  #pragma unroll
  for (int it = 0; it < 16; ++it) {
    int idx = tid + it * 256;          // 4096 = 32 k x 128 j
    int j = idx & 127, kl = idx >> 7;
    Ws[kl][j] = W[(kk + kl) * 128 + j];
  }
}

__device__ __forceinline__ void stage_W_tt(const float* __restrict__ W, float (&Ws)[KC][132],
                                           int kk, int tid) {
  #pragma unroll
  for (int it = 0; it < 16; ++it) {
    int idx = tid + it * 256;
    int kl = idx & 31, j = idx >> 5;
    Ws[kl][j] = W[(long long)j * 128 + kk + kl];
  }
}

__device__ __forceinline__ void kloop64(const float (&At)[KC][68], const float (&Ws)[KC][132],
                                        float (&acc)[4][8], int rr, int cl, int ch) {
  #pragma unroll 4
  for (int k = 0; k < KC; ++k) {
    float4 a0 = *(const float4*)&At[k][rr];
    float4 w0 = *(const float4*)&Ws[k][cl];
    float4 w1 = *(const float4*)&Ws[k][ch];
    float a[4] = {a0.x, a0.y, a0.z, a0.w};
    float w[8] = {w0.x, w0.y, w0.z, w0.w, w1.x, w1.y, w1.z, w1.w};
    #pragma unroll
    for (int i = 0; i < 4; ++i)
      #pragma unroll
      for (int j = 0; j < 8; ++j)
        acc[i][j] = fmaf(a[i], w[j], acc[i][j]);
  }
}

__device__ __forceinline__ void kloop64d(const float (&At)[KC][68],
                                         const float (&W1)[KC][132], const float (&W2)[KC][132],
                                         float (&a1)[4][8], float (&a2)[4][8], int rr, int cl, int ch) {
  #pragma unroll 2
  for (int k = 0; k < KC; ++k) {
    float4 a0 = *(const float4*)&At[k][rr];
    float4 u0 = *(const float4*)&W1[k][cl];
    float4 u1 = *(const float4*)&W1[k][ch];
    float4 v0 = *(const float4*)&W2[k][cl];
    float4 v1 = *(const float4*)&W2[k][ch];
    float a[4] = {a0.x, a0.y, a0.z, a0.w};
    float u[8] = {u0.x, u0.y, u0.z, u0.w, u1.x, u1.y, u1.z, u1.w};
    float v[8] = {v0.x, v0.y, v0.z, v0.w, v1.x, v1.y, v1.z, v1.w};
    #pragma unroll
    for (int i = 0; i < 4; ++i)
      #pragma unroll
      for (int j = 0; j < 8; ++j) {
        a1[i][j] = fmaf(a[i], u[j], a1[i][j]);
        a2[i][j] = fmaf(a[i], v[j], a2[i][j]);
      }
  }
}

// V=0: Cout = A1@W1g (W [k][j])
// V=2: acc = A1@W1g^T (hp@Whh_n); acc = Rg*(acc+bmid); acc += A2@W2g^T (q@Wih_n);
//      out = (1-Zg)*tanh(acc+bend1) + Zg*HPg -> O[.] and O[NH+.]
template<int V>
__global__ __launch_bounds__(256) void k_gemm(
    const float* __restrict__ A1, const float* __restrict__ W1g,
    const float* __restrict__ A2, const float* __restrict__ W2g,
    const float* __restrict__ bmid, const float* __restrict__ bend1,
    const float* __restrict__ Rg, const float* __restrict__ Zg, const float* __restrict__ HPg,
    float* __restrict__ Cout, long long NH, int nrows)
{
  __shared__ float At[KC][68];
  __shared__ float Ws[KC][132];
  const int tid = threadIdx.x;
  const int r0 = blockIdx.x * 64;
  const int tr = tid >> 4, tc = tid & 15;
  const int rr = tr * 4;
  const int cl = tc * 4, ch = 64 + tc * 4;

  float acc[4][8];
  #pragma unroll
  for (int i = 0; i < 4; ++i)
    #pragma unroll
    for (int j = 0; j < 8; ++j) acc[i][j] = 0.f;

  for (int kk = 0; kk < 128; kk += KC) {
    stage_A64(A1, At, r0, kk, nrows, tid);
    if (V == 0) stage_W_nn(W1g, Ws, kk, tid);
    else        stage_W_tt(W1g, Ws, kk, tid);
    __syncthreads();
    kloop64(At, Ws, acc, rr, cl, ch);
    __syncthreads();
  }

  if (V == 2) {
    float4 bm0 = *(const float4*)&bmid[cl];
    float4 bm1 = *(const float4*)&bmid[ch];
    float bm[8] = {bm0.x, bm0.y, bm0.z, bm0.w, bm1.x, bm1.y, bm1.z, bm1.w};
    #pragma unroll
    for (int i = 0; i < 4; ++i) {
      int gr = r0 + rr + i;
      if (gr < nrows) {
        float4 rl = *(const float4*)&Rg[(long long)gr * 128 + cl];
        float4 rh = *(const float4*)&Rg[(long long)gr * 128 + ch];
        float rv[8] = {rl.x, rl.y, rl.z, rl.w, rh.x, rh.y, rh.z, rh.w};
        #pragma unroll
        for (int j = 0; j < 8; ++j) acc[i][j] = rv[j] * (acc[i][j] + bm[j]);
      }
    }
    for (int kk = 0; kk < 128; kk += KC) {
      stage_A64(A2, At, r0, kk, nrows, tid);
      stage_W_tt(W2g, Ws, kk, tid);
      __syncthreads();
      kloop64(At, Ws, acc, rr, cl, ch);
      __syncthreads();
    }
  }

  if (V == 0) {
    #pragma unroll
    for (int i = 0; i < 4; ++i) {
      int gr = r0 + rr + i;
      if (gr < nrows) {
        *(float4*)&Cout[(long long)gr * 128 + cl] = make_float4(acc[i][0], acc[i][1], acc[i][2], acc[i][3]);
        *(float4*)&Cout[(long long)gr * 128 + ch] = make_float4(acc[i][4], acc[i][5], acc[i][6], acc[i][7]);
      }
    }
  } else {
    float4 x0 = *(const float4*)&bend1[cl], x1 = *(const float4*)&bend1[ch];
    float b[8] = {x0.x, x0.y, x0.z, x0.w, x1.x, x1.y, x1.z, x1.w};
    #pragma unroll
    for (int i = 0; i < 4; ++i) {
      int gr = r0 + rr + i;
      if (gr < nrows) {
        long long base = (long long)gr * 128;
        float4 zl = *(const float4*)&Zg[base + cl];
        float4 zh = *(const float4*)&Zg[base + ch];
        float4 hl = *(const float4*)&HPg[base + cl];
        float4 hh = *(const float4*)&HPg[base + ch];
        float zv[8] = {zl.x, zl.y, zl.z, zl.w, zh.x, zh.y, zh.z, zh.w};
        float hv[8] = {hl.x, hl.y, hl.z, hl.w, hh.x, hh.y, hh.z, hh.w};
        float o[8];
        #pragma unroll
        for (int j = 0; j < 8; ++j) {
          float n = tanhf(acc[i][j] + b[j]);
          o[j] = (1.0f - zv[j]) * n + zv[j] * hv[j];
        }
        // each thread reads its own R/Z slots above, then overwrites below
        *(float4*)&Cout[base + cl] = make_float4(o[0], o[1], o[2], o[3]);
        *(float4*)&Cout[base + ch] = make_float4(o[4], o[5], o[6], o[7]);
        *(float4*)&Cout[NH + base + cl] = make_float4(o[0], o[1], o[2], o[3]);
        *(float4*)&Cout[NH + base + ch] = make_float4(o[4], o[5], o[6], o[7]);
      }
    }
  }
}

// fused R,Z gates: r = sig(q@Wih_r^T + hp@Whh_r^T + b), z likewise (rows 128..255)
__global__ __launch_bounds__(256) void k_gates(
    const float* __restrict__ q, const float* __restrict__ hp,
    const float* __restrict__ Wih, const float* __restrict__ Whh,
    const float* __restrict__ bih, const float* __restrict__ bhh,
    float* __restrict__ R, float* __restrict__ Z, int nrows)
{
  __shared__ float At[KC][68];
  __shared__ float W1[KC][132];
  __shared__ float W2[KC][132];
  const int tid = threadIdx.x;
  const int r0 = blockIdx.x * 64;
  const int tr = tid >> 4, tc = tid & 15;
  const int rr = tr * 4;
  const int cl = tc * 4, ch = 64 + tc * 4;

  float ar[4][8], az[4][8];
  #pragma unroll
  for (int i = 0; i < 4; ++i)
    #pragma unroll
    for (int j = 0; j < 8; ++j) { ar[i][j] = 0.f; az[i][j] = 0.f; }

  // phase 1: q against Wih_r (rows 0..127) and Wih_z (rows 128..255)
  for (int kk = 0; kk < 128; kk += KC) {
    stage_A64(q, At, r0, kk, nrows, tid);
    stage_W_tt(Wih, W1, kk, tid);
    stage_W_tt(Wih + 16384, W2, kk, tid);
    __syncthreads();
    kloop64d(At, W1, W2, ar, az, rr, cl, ch);
    __syncthreads();
  }
  // phase 2: hp against Whh_r and Whh_z
  for (int kk = 0; kk < 128; kk += KC) {
    stage_A64(hp, At, r0, kk, nrows, tid);
    stage_W_tt(Whh, W1, kk, tid);
    stage_W_tt(Whh + 16384, W2, kk, tid);
    __syncthreads();
    kloop64d(At, W1, W2, ar, az, rr, cl, ch);
    __syncthreads();
  }

  float4 br0 = *(const float4*)&bih[cl], br1 = *(const float4*)&bih[ch];
  float4 cr0 = *(const float4*)&bhh[cl], cr1 = *(const float4*)&bhh[ch];
  float4 bz0 = *(const float4*)&bih[128 + cl], bz1 = *(const float4*)&bih[128 + ch];
  float4 cz0 = *(const float4*)&bhh[128 + cl], cz1 = *(const float4*)&bhh[128 + ch];
  float brv[8] = {br0.x + cr0.x, br0.y + cr0.y, br0.z + cr0.z, br0.w + cr0.w,
                  br1.x + cr1.x, br1.y + cr1.y, br1.z + cr1.z, br1.w + cr1.w};
  float bzv[8] = {bz0.x + cz0.x, bz0.y + cz0.y, bz0.z + cz0.z, bz0.w + cz0.w,
                  bz1.x + cz1.x, bz1.y + cz1.y, bz1.z + cz1.z, bz1.w + cz1.w};
  #pragma unroll
  for (int i = 0; i < 4; ++i) {
    int gr = r0 + rr + i;
    if (gr < nrows) {
      long long base = (long long)gr * 128;
      *(float4*)&R[base + cl] = make_float4(sigf(ar[i][0] + brv[0]), sigf(ar[i][1] + brv[1]),
                                            sigf(ar[i][2] + brv[2]), sigf(ar[i][3] + brv[3]));
      *(float4*)&R[base + ch] = make_float4(sigf(ar[i][4] + brv[4]), sigf(ar[i][5] + brv[5]),
                                            sigf(ar[i][6] + brv[6]), sigf(ar[i][7] + brv[7]));
      *(float4*)&Z[base + cl] = make_float4(sigf(az[i][0] + bzv[0]), sigf(az[i][1] + bzv[1]),
                                            sigf(az[i][2] + bzv[2]), sigf(az[i][3] + bzv[3]));
      *(float4*)&Z[base + ch] = make_float4(sigf(az[i][4] + bzv[4]), sigf(az[i][5] + bzv[5]),
                                            sigf(az[i][6] + bzv[6]), sigf(az[i][7] + bzv[7]));
    }
  }
}

// ---------------- CSR gather (32-lane group per node, float4/lane) ----------------

template<bool FUSE_LN>
__global__ __launch_bounds__(256) void k_gather(
    const float* __restrict__ XW, const float* __restrict__ dinv,
    const int* __restrict__ offs, const int* __restrict__ ssrc,
    const float* __restrict__ bias,
    const float* __restrict__ H1,
    const float* __restrict__ gamma, const float* __restrict__ beta,
    float* __restrict__ Out, int nnodes)
{
  int g = (int)(((long long)blockIdx.x * blockDim.x + threadIdx.x) >> 5);
  int l = threadIdx.x & 31;
  if (g >= nnodes) return;
  float di = dinv[g];
  float4 acc = ((const float4*)(XW + (long long)g * 128))[l];
  acc.x *= di; acc.y *= di; acc.z *= di; acc.w *= di;

  int j = offs[g], e1 = offs[g + 1];
  for (; j + 1 < e1; j += 2) {
    int s0 = ssrc[j], s1 = ssrc[j + 1];
    float d0 = dinv[s0], d1 = dinv[s1];
    float4 v0 = ((const float4*)(XW + (long long)s0 * 128))[l];
    float4 v1 = ((const float4*)(XW + (long long)s1 * 128))[l];
    acc.x = fmaf(d0, v0.x, acc.x); acc.y = fmaf(d0, v0.y, acc.y);
    acc.z = fmaf(d0, v0.z, acc.z); acc.w = fmaf(d0, v0.w, acc.w);
    acc.x = fmaf(d1, v1.x, acc.x); acc.y = fmaf(d1, v1.y, acc.y);
    acc.z = fmaf(d1, v1.z, acc.z); acc.w = fmaf(d1, v1.w, acc.w);
  }
  if (j < e1) {
    int s = ssrc[j];
    float ds = dinv[s];
    float4 v = ((const float4*)(XW + (long long)s * 128))[l];
    acc.x = fmaf(ds, v.x, acc.x); acc.y = fmaf(ds, v.y, acc.y);
    acc.z = fmaf(ds, v.z, acc.z); acc.w = fmaf(ds, v.w, acc.w);
  }

  int c = l * 4;
  float4 b4 = *(const float4*)&bias[c];
  float4 t;
  t.x = fmaxf(fmaf(acc.x, di, b4.x), 0.f);
  t.y = fmaxf(fmaf(acc.y, di, b4.y), 0.f);
  t.z = fmaxf(fmaf(acc.z, di, b4.z), 0.f);
  t.w = fmaxf(fmaf(acc.w, di, b4.w), 0.f);

  if (!FUSE_LN) {
    ((float4*)(Out + (long long)g * 128))[l] = t;
  } else {
    float4 h4 = ((const float4*)(H1 + (long long)g * 128))[l];
    t.x += h4.x; t.y += h4.y; t.z += h4.z; t.w += h4.w;
    float s = t.x + t.y + t.z + t.w;
    #pragma unroll
    for (int off = 16; off > 0; off >>= 1) s += __shfl_xor(s, off, 32);
    float mu = s * (1.0f / 128.0f);
    float dx = t.x - mu, dy = t.y - mu, dz = t.z - mu, dw = t.w - mu;
    float q = dx * dx + dy * dy + dz * dz + dw * dw;
    #pragma unroll
    for (int off = 16; off > 0; off >>= 1) q += __shfl_xor(q, off, 32);
    float rstd = rsqrtf(q * (1.0f / 128.0f) + 1e-5f);
    float4 g4 = *(const float4*)&gamma[c];
    float4 be4 = *(const float4*)&beta[c];
    float4 o;
    o.x = dx * rstd * g4.x + be4.x;
    o.y = dy * rstd * g4.y + be4.y;
    o.z = dz * rstd * g4.z + be4.z;
    o.w = dw * rstd * g4.w + be4.w;
    ((float4*)(Out + (long long)g * 128))[l] = o;
  }
}

// ---------------- launch ----------------

extern "C" void kernel_launch(void* const* d_in, const int* in_sizes, int n_in,
                              void* d_out, int out_size, void* d_ws, size_t ws_size,
                              hipStream_t stream) {
  float* ofp = (float*)d_out;
  const int fb = (out_size + 255) / 256;

  if (n_in != 13) { k_fill<<<fb, 256, 0, stream>>>(ofp, out_size, 100.0f); return; }

  const int N = in_sizes[0] / 128;
  const int S1 = in_sizes[1];
  const int E = S1 / 2;
  const long long NH = (long long)N * 128;

  bool okp = (in_sizes[0] % 128 == 0) && (S1 % 4 == 0) &&
             (in_sizes[2] == in_sizes[0]) &&
             in_sizes[3] == 16384 && in_sizes[4] == 128 &&
             in_sizes[5] == 16384 && in_sizes[6] == 128 &&
             in_sizes[7] == 128 && in_sizes[8] == 128 &&
             in_sizes[9] == 49152 && in_sizes[10] == 49152 &&
             in_sizes[11] == 384 && in_sizes[12] == 384;
  if (!okp) { k_fill<<<fb, 256, 0, stream>>>(ofp, out_size, 50.0f); return; }

  // ws: dinv | hist | part | offs | cursor | bsum | ssrc | pad | Xf | Yf
  char* wsb = (char*)d_ws;
  float* dinv = (float*)wsb;
  int* hist   = (int*)(dinv + N);
  int* part   = hist + N;
  int* offs   = part + N;
  int* cursor = offs + N + 1;
  int* bsum   = cursor + N;
  int* ssrc   = bsum + 1024;
  size_t head = (size_t)((char*)(ssrc + E) - wsb);
  head = (head + 255) & ~(size_t)255;
  float* Xf = (float*)(wsb + head);
  float* Yf = Xf + NH;
  size_t need = head + (size_t)2 * NH * 4;
  if (ws_size < need) { k_fill<<<fb, 256, 0, stream>>>(ofp, out_size, 25.0f); return; }

  const float* x   = (const float*)d_in[0];
  const int*   ei  = (const int*)d_in[1];
  const float* hp  = (const float*)d_in[2];
  const float* W1  = (const float*)d_in[3];
  const float* b1  = (const float*)d_in[4];
  const float* W2  = (const float*)d_in[5];
  const float* b2  = (const float*)d_in[6];
  const float* gam = (const float*)d_in[7];
  const float* bet = (const float*)d_in[8];
  const float* Wih = (const float*)d_in[9];
  const float* Whh = (const float*)d_in[10];
  const float* bih = (const float*)d_in[11];
  const float* bhh = (const float*)d_in[12];
  const int* srcp = ei;
  const int* dstp = ei + E;

  float* Rbuf = ofp;        // d_out first half as R scratch
  float* Zbuf = ofp + NH;   // d_out second half as Z scratch

  const int eb  = (E + 255) / 256;
  const int nb  = (N + 255) / 256;
  const int gb  = (N + 63) / 64;
  const int agb = (int)(((long long)N * 32 + 255) / 256);

  // CSR build + dinv
  hipMemsetAsync(hist, 0, (size_t)N * sizeof(int), stream);
  k_hist<<<eb, 256, 0, stream>>>(dstp, hist, E);
  k_scan1<<<nb, 256, 0, stream>>>(hist, part, bsum, N);
  k_scan2<<<1, 512, 0, stream>>>(bsum, nb);
  k_scan3<<<nb + 1, 256, 0, stream>>>(part, bsum, hist, offs, cursor, dinv, N, E);
  k_sort<<<eb, 256, 0, stream>>>(srcp, dstp, cursor, ssrc, E);

  // conv1: Xf = x@W1 ; Yf = h1 = relu(gather + b1)
  k_gemm<0><<<gb, 256, 0, stream>>>(x, W1, nullptr, nullptr, nullptr, nullptr,
                                    nullptr, nullptr, nullptr, Xf, NH, N);
  k_gather<false><<<agb, 256, 0, stream>>>(Xf, dinv, offs, ssrc, b1,
                                           nullptr, nullptr, nullptr, Yf, N);
  // conv2: Xf = h1@W2 ; Yf = q = LN(h1 + relu(gather + b2))  (in-place)
  k_gemm<0><<<gb, 256, 0, stream>>>(Yf, W2, nullptr, nullptr, nullptr, nullptr,
                                    nullptr, nullptr, nullptr, Xf, NH, N);
  k_gather<true><<<agb, 256, 0, stream>>>(Xf, dinv, offs, ssrc, b2,
                                          Yf, gam, bet, Yf, N);

  // GRU: fused R,Z -> d_out halves, then fused n+output overwrites both
  k_gates<<<gb, 256, 0, stream>>>(Yf, hp, Wih, Whh, bih, bhh, Rbuf, Zbuf, N);
  k_gemm<2><<<gb, 256, 0, stream>>>(hp, Whh + 32768, Yf, Wih + 32768,
                                    bhh + 256, bih + 256,
                                    Rbuf, Zbuf, hp, ofp, NH, N);
}

// Round 27
// 996.828 us; speedup vs baseline: 1.1847x; 1.1847x over previous
//
#include <hip/hip_runtime.h>
#include <hip/hip_bf16.h>

// Round 27: MFMA GEMMs via split-bf16 (3-product: hh+hl+lh, ~2^-16 rel err).
// 128x128 tile, 4 waves, mfma_f32_16x16x32_bf16, KC=32. Weights pre-transposed
// + pre-split once (bf16 hi/lo, [j][k] layout). A split f32->hi/lo in LDS
// staging (pitch 40 bf16 for 16B-aligned frag reads). Fused epilogues:
// V0 plain, V1 sigmoid(two-phase), V2 full GRU n+output. CSR gather unchanged.

typedef unsigned short u16;
typedef __attribute__((ext_vector_type(8))) short short8v;
typedef __attribute__((ext_vector_type(4))) float float4v;

__device__ __forceinline__ float sigf(float x) { return 1.0f / (1.0f + __expf(-x)); }

__global__ __launch_bounds__(256) void k_fill(float* o, long long n, float v) {
  long long i = (long long)blockIdx.x * 256 + threadIdx.x;
  if (i < n) o[i] = v;
}

// ---------------- CSR build (pairing A: src=ei[e], dst=ei[E+e]) ----------------

__global__ __launch_bounds__(256) void k_hist(const int* __restrict__ dstp, int* __restrict__ hist, int E) {
  int e = blockIdx.x * 256 + threadIdx.x;
  if (e < E) atomicAdd(&hist[dstp[e]], 1);
}

__global__ __launch_bounds__(256) void k_scan1(const int* __restrict__ hist, int* __restrict__ part,
                                               int* __restrict__ bsum, int n) {
  __shared__ int sh[256];
  int tid = threadIdx.x;
  int i = blockIdx.x * 256 + tid;
  int v = (i < n) ? hist[i] : 0;
  sh[tid] = v; __syncthreads();
  for (int off = 1; off < 256; off <<= 1) {
    int t = (tid >= off) ? sh[tid - off] : 0;
    __syncthreads();
    sh[tid] += t;
    __syncthreads();
  }
  if (i < n) part[i] = sh[tid] - v;
  if (tid == 255) bsum[blockIdx.x] = sh[255];
}

__global__ __launch_bounds__(512) void k_scan2(int* bs, int nb) {
  __shared__ int sh[512];
  int tid = threadIdx.x;
  int v = (tid < nb) ? bs[tid] : 0;
  sh[tid] = v; __syncthreads();
  for (int off = 1; off < 512; off <<= 1) {
    int t = (tid >= off) ? sh[tid - off] : 0;
    __syncthreads();
    sh[tid] += t;
    __syncthreads();
  }
  if (tid < nb) bs[tid] = sh[tid] - v;
}

__global__ __launch_bounds__(256) void k_scan3(const int* __restrict__ part, const int* __restrict__ bs,
                                               const int* __restrict__ hist, int* __restrict__ offs,
                                               int* __restrict__ cursor, float* __restrict__ dinv,
                                               int n, int E) {
  int i = blockIdx.x * 256 + threadIdx.x;
  if (i < n) {
    int o = part[i] + bs[i >> 8];
    offs[i] = o;
    cursor[i] = o;
    dinv[i] = rsqrtf((float)hist[i] + 1.0f);   // +1 self-loop
  } else if (i == n) {
    offs[n] = E;
  }
}

__global__ __launch_bounds__(256) void k_sort(const int* __restrict__ srcp, const int* __restrict__ dstp,
                                              int* cursor, int* __restrict__ ssrc, int E) {
  int e = blockIdx.x * 256 + threadIdx.x;
  if (e < E) {
    int d = dstp[e];
    int pos = atomicAdd(&cursor[d], 1);
    ssrc[pos] = srcp[e];
  }
}

// ---------------- weight prep: [j][k] bf16 hi/lo splits ----------------
// T=1: conv W stored [k][j] -> transpose.  T=0: gru W already [j][k].
__global__ __launch_bounds__(256) void k_prepW(const float* __restrict__ Win,
                                               u16* __restrict__ Whi, u16* __restrict__ Wlo,
                                               int rows, int T) {
  int idx = blockIdx.x * 256 + threadIdx.x;
  if (idx >= rows * 128) return;
  int j = idx >> 7, k = idx & 127;
  float f = T ? Win[(long long)k * 128 + j] : Win[idx];
  __hip_bfloat16 h = __float2bfloat16(f);
  float hf = __bfloat162float(h);
  __hip_bfloat16 lo = __float2bfloat16(f - hf);
  Whi[idx] = *(u16*)&h;
  Wlo[idx] = *(u16*)&lo;
}

// ---------------- MFMA GEMM (128x128 tile, 4 waves, KC=32) ----------------
// A f32 (split to hi/lo bf16 during LDS staging); W pre-split [j][k] global.
// frag layouts (16x16x32 bf16): A row=l&15, k=(l>>4)*8+i ; B col=l&15, same k.
// C/D: col=l&15, row=(l>>4)*4+reg  [guide-verified].

#define AP 40   // LDS row pitch (bf16) -> 80B rows, 16B-aligned frags

template<int V>
__global__ __launch_bounds__(256) void k_mgemm(
    const float* __restrict__ A1, const u16* __restrict__ W1hi, const u16* __restrict__ W1lo,
    const float* __restrict__ A2, const u16* __restrict__ W2hi, const u16* __restrict__ W2lo,
    const float* __restrict__ bmid, const float* __restrict__ b1, const float* __restrict__ b2,
    const float* __restrict__ Rg, const float* __restrict__ Zg, const float* __restrict__ HPg,
    float* __restrict__ Cout, long long NH, int nrows)
{
  __shared__ u16 Ahi[128 * AP], Alo[128 * AP], Bhi[128 * AP], Blo[128 * AP];
  const int tid = threadIdx.x;
  const int w = tid >> 6, l = tid & 63;
  const int r0 = blockIdx.x * 128;
  const int lrow = l & 15;            // frag row (A) / col (B)
  const int lk = (l >> 4) * 8;        // frag k-base
  const int rb = (l >> 4) * 4;        // C/D row base
  const int lc = l & 15;              // C/D col

  float4v acc[2][8];
  #pragma unroll
  for (int rt = 0; rt < 2; ++rt)
    #pragma unroll
    for (int ct = 0; ct < 8; ++ct) acc[rt][ct] = (float4v){0.f, 0.f, 0.f, 0.f};

  // stage A chunk (128 rows x 32 k) with on-the-fly hi/lo split
  auto stageA = [&](const float* __restrict__ A, int kk) {
    int r = tid >> 1;
    int kl = (tid & 1) * 16;
    bool ok = (r0 + r) < nrows;
    const float* src = A + (long long)(r0 + r) * 128 + kk + kl;
    u16 hbuf[16], lbuf[16];
    #pragma unroll
    for (int p = 0; p < 16; ++p) {
      float f = ok ? src[p] : 0.f;
      __hip_bfloat16 h = __float2bfloat16(f);
      float hf = __bfloat162float(h);
      __hip_bfloat16 lo = __float2bfloat16(f - hf);
      hbuf[p] = *(u16*)&h;
      lbuf[p] = *(u16*)&lo;
    }
    *(uint4*)&Ahi[r * AP + kl]     = *(uint4*)&hbuf[0];
    *(uint4*)&Ahi[r * AP + kl + 8] = *(uint4*)&hbuf[8];
    *(uint4*)&Alo[r * AP + kl]     = *(uint4*)&lbuf[0];
    *(uint4*)&Alo[r * AP + kl + 8] = *(uint4*)&lbuf[8];
  };

  // stage W chunk (128 j x 32 k) from pre-split global
  auto stageW = [&](const u16* __restrict__ Ghi, const u16* __restrict__ Glo, int kk) {
    int j = tid >> 1;
    int kl = (tid & 1) * 16;
    long long g = (long long)j * 128 + kk + kl;
    *(uint4*)&Bhi[j * AP + kl]     = *(const uint4*)&Ghi[g];
    *(uint4*)&Bhi[j * AP + kl + 8] = *(const uint4*)&Ghi[g + 8];
    *(uint4*)&Blo[j * AP + kl]     = *(const uint4*)&Glo[g];
    *(uint4*)&Blo[j * AP + kl + 8] = *(const uint4*)&Glo[g + 8];
  };

  auto phase = [&](const float* __restrict__ A, const u16* __restrict__ Ghi,
                   const u16* __restrict__ Glo) {
    for (int kk = 0; kk < 128; kk += 32) {
      stageA(A, kk);
      stageW(Ghi, Glo, kk);
      __syncthreads();
      short8v af[2][2];
      #pragma unroll
      for (int rt = 0; rt < 2; ++rt) {
        int row = w * 32 + rt * 16 + lrow;
        af[rt][0] = *(short8v*)&Ahi[row * AP + lk];
        af[rt][1] = *(short8v*)&Alo[row * AP + lk];
      }
      #pragma unroll
      for (int ct = 0; ct < 8; ++ct) {
        int col = ct * 16 + lrow;
        short8v bh = *(short8v*)&Bhi[col * AP + lk];
        short8v bl = *(short8v*)&Blo[col * AP + lk];
        #pragma unroll
        for (int rt = 0; rt < 2; ++rt) {
          acc[rt][ct] = __builtin_amdgcn_mfma_f32_16x16x32_bf16(af[rt][0], bh, acc[rt][ct], 0, 0, 0);
          acc[rt][ct] = __builtin_amdgcn_mfma_f32_16x16x32_bf16(af[rt][0], bl, acc[rt][ct], 0, 0, 0);
          acc[rt][ct] = __builtin_amdgcn_mfma_f32_16x16x32_bf16(af[rt][1], bh, acc[rt][ct], 0, 0, 0);
        }
      }
      __syncthreads();
    }
  };

  phase(A1, W1hi, W1lo);

  if (V == 2) {
    // acc = R * (acc + bmid)
    #pragma unroll
    for (int ct = 0; ct < 8; ++ct) {
      int col = ct * 16 + lc;
      float bm = bmid[col];
      #pragma unroll
      for (int rt = 0; rt < 2; ++rt) {
        #pragma unroll
        for (int p = 0; p < 4; ++p) {
          int gr = r0 + w * 32 + rt * 16 + rb + p;
          int grc = (gr < nrows) ? gr : (nrows - 1);
          float r = Rg[(long long)grc * 128 + col];
          acc[rt][ct][p] = r * (acc[rt][ct][p] + bm);
        }
      }
    }
  }
  if (V >= 1) phase(A2, W2hi, W2lo);

  if (V == 0) {
    #pragma unroll
    for (int ct = 0; ct < 8; ++ct) {
      int col = ct * 16 + lc;
      #pragma unroll
      for (int rt = 0; rt < 2; ++rt)
        #pragma unroll
        for (int p = 0; p < 4; ++p) {
          int gr = r0 + w * 32 + rt * 16 + rb + p;
          if (gr < nrows) Cout[(long long)gr * 128 + col] = acc[rt][ct][p];
        }
    }
  } else if (V == 1) {
    #pragma unroll
    for (int ct = 0; ct < 8; ++ct) {
      int col = ct * 16 + lc;
      float bb = b1[col] + b2[col];
      #pragma unroll
      for (int rt = 0; rt < 2; ++rt)
        #pragma unroll
        for (int p = 0; p < 4; ++p) {
          int gr = r0 + w * 32 + rt * 16 + rb + p;
          if (gr < nrows) Cout[(long long)gr * 128 + col] = sigf(acc[rt][ct][p] + bb);
        }
    }
  } else {
    #pragma unroll
    for (int ct = 0; ct < 8; ++ct) {
      int col = ct * 16 + lc;
      float bn = b1[col];
      #pragma unroll
      for (int rt = 0; rt < 2; ++rt)
        #pragma unroll
        for (int p = 0; p < 4; ++p) {
          int gr = r0 + w * 32 + rt * 16 + rb + p;
          if (gr < nrows) {
            long long o = (long long)gr * 128 + col;
            float z = Zg[o];
            float h = HPg[o];
            float n = tanhf(acc[rt][ct][p] + bn);
            float out = (1.0f - z) * n + z * h;
            Cout[o] = out;          // own slot: read Z above, then overwrite
            Cout[NH + o] = out;
          }
        }
    }
  }
}

// ---------------- CSR gather (32-lane group per node, float4/lane) ----------------

template<bool FUSE_LN>
__global__ __launch_bounds__(256) void k_gather(
    const float* __restrict__ XW, const float* __restrict__ dinv,
    const int* __restrict__ offs, const int* __restrict__ ssrc,
    const float* __restrict__ bias,
    const float* __restrict__ H1,
    const float* __restrict__ gamma, const float* __restrict__ beta,
    float* __restrict__ Out, int nnodes)
{
  int g = (int)(((long long)blockIdx.x * blockDim.x + threadIdx.x) >> 5);
  int l = threadIdx.x & 31;
  if (g >= nnodes) return;
  float di = dinv[g];
  float4 acc = ((const float4*)(XW + (long long)g * 128))[l];
  acc.x *= di; acc.y *= di; acc.z *= di; acc.w *= di;

  int j = offs[g], e1 = offs[g + 1];
  for (; j + 1 < e1; j += 2) {
    int s0 = ssrc[j], s1 = ssrc[j + 1];
    float d0 = dinv[s0], d1 = dinv[s1];
    float4 v0 = ((const float4*)(XW + (long long)s0 * 128))[l];
    float4 v1 = ((const float4*)(XW + (long long)s1 * 128))[l];
    acc.x = fmaf(d0, v0.x, acc.x); acc.y = fmaf(d0, v0.y, acc.y);
    acc.z = fmaf(d0, v0.z, acc.z); acc.w = fmaf(d0, v0.w, acc.w);
    acc.x = fmaf(d1, v1.x, acc.x); acc.y = fmaf(d1, v1.y, acc.y);
    acc.z = fmaf(d1, v1.z, acc.z); acc.w = fmaf(d1, v1.w, acc.w);
  }
  if (j < e1) {
    int s = ssrc[j];
    float ds = dinv[s];
    float4 v = ((const float4*)(XW + (long long)s * 128))[l];
    acc.x = fmaf(ds, v.x, acc.x); acc.y = fmaf(ds, v.y, acc.y);
    acc.z = fmaf(ds, v.z, acc.z); acc.w = fmaf(ds, v.w, acc.w);
  }

  int c = l * 4;
  float4 b4 = *(const float4*)&bias[c];
  float4 t;
  t.x = fmaxf(fmaf(acc.x, di, b4.x), 0.f);
  t.y = fmaxf(fmaf(acc.y, di, b4.y), 0.f);
  t.z = fmaxf(fmaf(acc.z, di, b4.z), 0.f);
  t.w = fmaxf(fmaf(acc.w, di, b4.w), 0.f);

  if (!FUSE_LN) {
    ((float4*)(Out + (long long)g * 128))[l] = t;
  } else {
    float4 h4 = ((const float4*)(H1 + (long long)g * 128))[l];
    t.x += h4.x; t.y += h4.y; t.z += h4.z; t.w += h4.w;
    float s = t.x + t.y + t.z + t.w;
    #pragma unroll
    for (int off = 16; off > 0; off >>= 1) s += __shfl_xor(s, off, 32);
    float mu = s * (1.0f / 128.0f);
    float dx = t.x - mu, dy = t.y - mu, dz = t.z - mu, dw = t.w - mu;
    float q = dx * dx + dy * dy + dz * dz + dw * dw;
    #pragma unroll
    for (int off = 16; off > 0; off >>= 1) q += __shfl_xor(q, off, 32);
    float rstd = rsqrtf(q * (1.0f / 128.0f) + 1e-5f);
    float4 g4 = *(const float4*)&gamma[c];
    float4 be4 = *(const float4*)&beta[c];
    float4 o;
    o.x = dx * rstd * g4.x + be4.x;
    o.y = dy * rstd * g4.y + be4.y;
    o.z = dz * rstd * g4.z + be4.z;
    o.w = dw * rstd * g4.w + be4.w;
    ((float4*)(Out + (long long)g * 128))[l] = o;
  }
}

// ---------------- launch ----------------

extern "C" void kernel_launch(void* const* d_in, const int* in_sizes, int n_in,
                              void* d_out, int out_size, void* d_ws, size_t ws_size,
                              hipStream_t stream) {
  float* ofp = (float*)d_out;
  const int fb = (out_size + 255) / 256;

  if (n_in != 13) { k_fill<<<fb, 256, 0, stream>>>(ofp, out_size, 100.0f); return; }

  const int N = in_sizes[0] / 128;
  const int S1 = in_sizes[1];
  const int E = S1 / 2;
  const long long NH = (long long)N * 128;

  bool okp = (in_sizes[0] % 128 == 0) && (S1 % 4 == 0) &&
             (in_sizes[2] == in_sizes[0]) &&
             in_sizes[3] == 16384 && in_sizes[4] == 128 &&
             in_sizes[5] == 16384 && in_sizes[6] == 128 &&
             in_sizes[7] == 128 && in_sizes[8] == 128 &&
             in_sizes[9] == 49152 && in_sizes[10] == 49152 &&
             in_sizes[11] == 384 && in_sizes[12] == 384;
  if (!okp) { k_fill<<<fb, 256, 0, stream>>>(ofp, out_size, 50.0f); return; }

  // ws: dinv | hist | part | offs | cursor | bsum | ssrc | Wsplits | pad | Xf | Yf
  char* wsb = (char*)d_ws;
  float* dinv = (float*)wsb;
  int* hist   = (int*)(dinv + N);
  int* part   = hist + N;
  int* offs   = part + N;
  int* cursor = offs + N + 1;
  int* bsum   = cursor + N;
  int* ssrc   = bsum + 1024;
  size_t wofs = (size_t)((char*)(ssrc + E) - wsb);
  wofs = (wofs + 255) & ~(size_t)255;
  u16* w1thi = (u16*)(wsb + wofs);
  u16* w1tlo = w1thi + 16384;
  u16* w2thi = w1tlo + 16384;
  u16* w2tlo = w2thi + 16384;
  u16* wihhi = w2tlo + 16384;
  u16* wihlo = wihhi + 49152;
  u16* whhhi = wihlo + 49152;
  u16* whhlo = whhhi + 49152;
  size_t head = (size_t)((char*)(whhlo + 49152) - wsb);
  head = (head + 255) & ~(size_t)255;
  float* Xf = (float*)(wsb + head);
  float* Yf = Xf + NH;
  size_t need = head + (size_t)2 * NH * 4;
  if (ws_size < need) { k_fill<<<fb, 256, 0, stream>>>(ofp, out_size, 25.0f); return; }

  const float* x   = (const float*)d_in[0];
  const int*   ei  = (const int*)d_in[1];
  const float* hp  = (const float*)d_in[2];
  const float* W1  = (const float*)d_in[3];
  const float* b1  = (const float*)d_in[4];
  const float* W2  = (const float*)d_in[5];
  const float* b2  = (const float*)d_in[6];
  const float* gam = (const float*)d_in[7];
  const float* bet = (const float*)d_in[8];
  const float* Wih = (const float*)d_in[9];
  const float* Whh = (const float*)d_in[10];
  const float* bih = (const float*)d_in[11];
  const float* bhh = (const float*)d_in[12];
  const int* srcp = ei;
  const int* dstp = ei + E;

  float* Rbuf = ofp;        // d_out first half as R scratch
  float* Zbuf = ofp + NH;   // d_out second half as Z scratch

  const int eb  = (E + 255) / 256;
  const int nb  = (N + 255) / 256;
  const int gb  = (N + 127) / 128;
  const int agb = (int)(((long long)N * 32 + 255) / 256);

  // weight prep (once per launch; tiny)
  k_prepW<<<64, 256, 0, stream>>>(W1, w1thi, w1tlo, 128, 1);
  k_prepW<<<64, 256, 0, stream>>>(W2, w2thi, w2tlo, 128, 1);
  k_prepW<<<192, 256, 0, stream>>>(Wih, wihhi, wihlo, 384, 0);
  k_prepW<<<192, 256, 0, stream>>>(Whh, whhhi, whhlo, 384, 0);

  // CSR build + dinv
  hipMemsetAsync(hist, 0, (size_t)N * sizeof(int), stream);
  k_hist<<<eb, 256, 0, stream>>>(dstp, hist, E);
  k_scan1<<<nb, 256, 0, stream>>>(hist, part, bsum, N);
  k_scan2<<<1, 512, 0, stream>>>(bsum, nb);
  k_scan3<<<nb + 1, 256, 0, stream>>>(part, bsum, hist, offs, cursor, dinv, N, E);
  k_sort<<<eb, 256, 0, stream>>>(srcp, dstp, cursor, ssrc, E);

  // conv1: Xf = x@W1 ; Yf = h1 = relu(gather + b1)
  k_mgemm<0><<<gb, 256, 0, stream>>>(x, w1thi, w1tlo, nullptr, nullptr, nullptr,
                                     nullptr, nullptr, nullptr,
                                     nullptr, nullptr, nullptr, Xf, NH, N);
  k_gather<false><<<agb, 256, 0, stream>>>(Xf, dinv, offs, ssrc, b1,
                                           nullptr, nullptr, nullptr, Yf, N);
  // conv2: Xf = h1@W2 ; Yf = q = LN(h1 + relu(gather + b2))  (in-place)
  k_mgemm<0><<<gb, 256, 0, stream>>>(Yf, w2thi, w2tlo, nullptr, nullptr, nullptr,
                                     nullptr, nullptr, nullptr,
                                     nullptr, nullptr, nullptr, Xf, NH, N);
  k_gather<true><<<agb, 256, 0, stream>>>(Xf, dinv, offs, ssrc, b2,
                                          Yf, gam, bet, Yf, N);

  // GRU gates: R and Z (each: q@Wih_g + hp@Whh_g + biases, sigmoid)
  k_mgemm<1><<<gb, 256, 0, stream>>>(Yf, wihhi, wihlo, hp, whhhi, whhlo,
                                     nullptr, bih, bhh,
                                     nullptr, nullptr, nullptr, Rbuf, NH, N);
  k_mgemm<1><<<gb, 256, 0, stream>>>(Yf, wihhi + 16384, wihlo + 16384,
                                     hp, whhhi + 16384, whhlo + 16384,
                                     nullptr, bih + 128, bhh + 128,
                                     nullptr, nullptr, nullptr, Zbuf, NH, N);
  // final: acc = hp@Whh_n ; acc = R*(acc+bhh_n) ; acc += q@Wih_n ;
  //        out = (1-Z)*tanh(acc+bih_n) + Z*hp  (both halves)
  k_mgemm<2><<<gb, 256, 0, stream>>>(hp, whhhi + 32768, whhlo + 32768,
                                     Yf, wihhi + 32768, wihlo + 32768,
                                     bhh + 256, bih + 256, nullptr,
                                     Rbuf, Zbuf, hp, ofp, NH, N);
}